// Round 3
// baseline (452.839 us; speedup 1.0000x reference)
//
#include <hip/hip_runtime.h>
#include <math.h>

// Problem constants
constexpr int Bc  = 32;
constexpr int Cc  = 1024;
constexpr int Mc  = 1024;
constexpr int Dc  = 512;
constexpr int DVc = 512;
constexpr int Rc  = 64;

// ---------------------------------------------------------------------------
// Row-sum: out[row] = sum_j X[row*1024 + j], one wave per row (1024 cols).
// Wave loops 4x: each iter reads 64 lanes x float4 = 1KB contiguous.
// Block = 256 = 4 rows.
// ---------------------------------------------------------------------------
__global__ __launch_bounds__(256) void k_rowsum(const float* __restrict__ X,
                                                float* __restrict__ out, int nrows) {
    const int row  = blockIdx.x * 4 + (threadIdx.x >> 6);
    const int lane = threadIdx.x & 63;
    if (row >= nrows) return;
    const float* xr = X + (long)row * 1024;
    float s = 0.f;
#pragma unroll
    for (int k = 0; k < 4; ++k) {
        float4 t = *(const float4*)&xr[k * 256 + lane * 4];
        s += (t.x + t.y) + (t.z + t.w);
    }
#pragma unroll
    for (int off = 32; off; off >>= 1) s += __shfl_down(s, off, 64);
    if (lane == 0) out[row] = s;
}

// ---------------------------------------------------------------------------
// Ksum[b,d] = sum_c Tsum[b,c]*Wk[c,d];  Vsum likewise with Wv.
// Thread = (b,d); lanes span consecutive d -> coalesced Wk/Wv reads;
// Tsum[b,c] wave-uniform. Grid = B*D/256 = 64 blocks.
// ---------------------------------------------------------------------------
__global__ __launch_bounds__(256) void k_kvsum(const float* __restrict__ Tsum,
                                               const float* __restrict__ Wk,
                                               const float* __restrict__ Wv,
                                               float* __restrict__ Ksum,
                                               float* __restrict__ Vsum) {
    const int gid = blockIdx.x * 256 + threadIdx.x;
    const int b = gid >> 9;        // 512 d per b
    const int d = gid & 511;
    const float* ts = Tsum + b * Cc;
    float ak = 0.f, av = 0.f;
#pragma unroll 4
    for (int c = 0; c < Cc; ++c) {
        float t = ts[c];
        ak = fmaf(t, Wk[(long)c * Dc + d], ak);
        av = fmaf(t, Wv[(long)c * DVc + d], av);
    }
    Ksum[gid] = ak;
    Vsum[gid] = av;
}

// ---------------------------------------------------------------------------
// wqk[b,c] = sum_d Wq[c,d]*Ksum[b,d];  vw[b,c] = sum_d Wout[d,c]*Vsum[b,d].
// Thread = (b,c). Wq: per-thread row stream (float4); Wout: coalesced.
// Grid = B*C/256 = 128 blocks.
// ---------------------------------------------------------------------------
__global__ __launch_bounds__(256) void k_wqkvw(const float* __restrict__ Ksum,
                                               const float* __restrict__ Vsum,
                                               const float* __restrict__ Wq,
                                               const float* __restrict__ Wout,
                                               float* __restrict__ wqk,
                                               float* __restrict__ vw) {
    const int gid = blockIdx.x * 256 + threadIdx.x;
    const int b = gid >> 10;       // 1024 c per b
    const int c = gid & 1023;
    const float* ks = Ksum + b * Dc;
    const float* vs = Vsum + b * DVc;
    const float* wqrow = Wq + (long)c * Dc;
    float aq = 0.f, av = 0.f;
#pragma unroll 2
    for (int d = 0; d < Dc; d += 4) {
        float4 w4 = *(const float4*)&wqrow[d];
        aq = fmaf(w4.x, ks[d],     aq);
        aq = fmaf(w4.y, ks[d + 1], aq);
        aq = fmaf(w4.z, ks[d + 2], aq);
        aq = fmaf(w4.w, ks[d + 3], aq);
        av = fmaf(Wout[(long)(d    ) * Cc + c], vs[d],     av);
        av = fmaf(Wout[(long)(d + 1) * Cc + c], vs[d + 1], av);
        av = fmaf(Wout[(long)(d + 2) * Cc + c], vs[d + 2], av);
        av = fmaf(Wout[(long)(d + 3) * Cc + c], vs[d + 3], av);
    }
    wqk[gid] = aq;
    vw[gid]  = av;
}

// ---------------------------------------------------------------------------
// Fused final: per (b, 64-m tile):
//   qk[i]  = sum_c T[b,c,i] * wqk[b,c]          (c split 16 ways, float4 on m)
//   w[i]   = sum_r softmax_r(scale*qk[i]*rsum[r]) * rsum[r]
//   Out[b,c,i] = w[i] * vw[b,c]                 (full c sweep, float4 on m)
// Block 256: il = tid&15 (m-quad), cs = tid>>4 (c-strip). Grid (M/64, B).
// ---------------------------------------------------------------------------
__global__ __launch_bounds__(256) void k_final(const float* __restrict__ T,
                                               const float* __restrict__ wqk,
                                               const float* __restrict__ vw,
                                               const float* __restrict__ rsum,
                                               float* __restrict__ Out,
                                               float scale) {
    __shared__ float rs[64];
    __shared__ float part[16][72];  // stride 72: 16B-aligned rows, conflict-free
    __shared__ float wsh[64];

    const int b  = blockIdx.y;
    const int m0 = blockIdx.x * 64;
    const int il = threadIdx.x & 15;
    const int cs = threadIdx.x >> 4;

    if (threadIdx.x < 64) rs[threadIdx.x] = rsum[threadIdx.x];

    const float* wq  = wqk + b * Cc;
    const float* Tbm = T + (long)b * Cc * Mc + m0 + il * 4;

    float4 acc = make_float4(0.f, 0.f, 0.f, 0.f);
#pragma unroll 4
    for (int c = cs; c < Cc; c += 16) {
        float4 t = *(const float4*)&Tbm[(long)c * Mc];
        float wc = wq[c];
        acc.x = fmaf(t.x, wc, acc.x);
        acc.y = fmaf(t.y, wc, acc.y);
        acc.z = fmaf(t.z, wc, acc.z);
        acc.w = fmaf(t.w, wc, acc.w);
    }
    *(float4*)&part[cs][il * 4] = acc;
    __syncthreads();

    if (threadIdx.x < 64) {
        const int i = threadIdx.x;
        float q = 0.f;
#pragma unroll
        for (int k = 0; k < 16; ++k) q += part[k][i];
        q *= scale;
        float mx = -1e30f;
#pragma unroll
        for (int r = 0; r < 64; ++r) mx = fmaxf(mx, q * rs[r]);
        float se = 0.f, sw = 0.f;
#pragma unroll
        for (int r = 0; r < 64; ++r) {
            float e = __expf(q * rs[r] - mx);
            se += e;
            sw = fmaf(e, rs[r], sw);
        }
        wsh[i] = sw / se;
    }
    __syncthreads();

    const float* vwb = vw + b * Cc;
    float* Ob = Out + (long)b * Cc * Mc + m0 + il * 4;
    float4 w4 = *(const float4*)&wsh[il * 4];
#pragma unroll 4
    for (int c = cs; c < Cc; c += 16) {
        float v = vwb[c];
        float4 o = make_float4(w4.x * v, w4.y * v, w4.z * v, w4.w * v);
        *(float4*)&Ob[(long)c * Mc] = o;
    }
}

extern "C" void kernel_launch(void* const* d_in, const int* in_sizes, int n_in,
                              void* d_out, int out_size, void* d_ws, size_t ws_size,
                              hipStream_t stream) {
    const float* T     = (const float*)d_in[0];  // (B,C,M)
    const float* Wq    = (const float*)d_in[1];  // (C,D)
    const float* Wk    = (const float*)d_in[2];  // (C,D)
    const float* Wv    = (const float*)d_in[3];  // (C,DV)
    const float* Wout  = (const float*)d_in[4];  // (DV,C)
    const float* Rfull = (const float*)d_in[5];  // (R,M)
    float* Out = (float*)d_out;

    float* ws   = (float*)d_ws;
    float* Tsum = ws;              // B*C   = 32768
    float* rsum = Tsum + Bc * Cc;  // R     = 64
    float* Ksum = rsum + Rc;       // B*D   = 16384
    float* Vsum = Ksum + Bc * Dc;  // B*DV  = 16384
    float* wqk  = Vsum + Bc * DVc; // B*C   = 32768
    float* vw   = wqk + Bc * Cc;   // B*C   = 32768

    // 1) Tsum[b,c] = sum_m T[b,c,m]   (rows = B*C, cols = M = 1024)
    k_rowsum<<<(Bc * Cc) / 4, 256, 0, stream>>>(T, Tsum, Bc * Cc);
    // 2) rsum[r] = sum_m R_full[r,m]  (rows = R = 64)
    k_rowsum<<<Rc / 4, 256, 0, stream>>>(Rfull, rsum, Rc);
    // 3) Ksum/Vsum
    k_kvsum<<<(Bc * Dc) / 256, 256, 0, stream>>>(Tsum, Wk, Wv, Ksum, Vsum);
    // 4) wqk/vw
    k_wqkvw<<<(Bc * Cc) / 256, 256, 0, stream>>>(Ksum, Vsum, Wq, Wout, wqk, vw);
    // 5) fused scores/softmax/output
    const float scale = 1.0f / sqrtf((float)Dc);
    k_final<<<dim3(Mc / 64, Bc), 256, 0, stream>>>(T, wqk, vw, rsum, Out, scale);
}

// Round 4
// 301.293 us; speedup vs baseline: 1.5030x; 1.5030x over previous
//
#include <hip/hip_runtime.h>
#include <math.h>

// Problem constants
constexpr int Bc  = 32;
constexpr int Cc  = 1024;
constexpr int Mc  = 1024;
constexpr int Dc  = 512;
constexpr int DVc = 512;
constexpr int Rc  = 64;

typedef float f4 __attribute__((ext_vector_type(4)));

// ---------------------------------------------------------------------------
// Row-sum (used for rsum only): out[row] = sum_j X[row*1024+j], wave per row.
// ---------------------------------------------------------------------------
__global__ __launch_bounds__(256) void k_rowsum(const float* __restrict__ X,
                                                float* __restrict__ out, int nrows) {
    const int row  = blockIdx.x * 4 + (threadIdx.x >> 6);
    const int lane = threadIdx.x & 63;
    if (row >= nrows) return;
    const float* xr = X + (long)row * 1024;
    float s = 0.f;
#pragma unroll
    for (int k = 0; k < 4; ++k) {
        float4 t = *(const float4*)&xr[k * 256 + lane * 4];
        s += (t.x + t.y) + (t.z + t.w);
    }
#pragma unroll
    for (int off = 32; off; off >>= 1) s += __shfl_down(s, off, 64);
    if (lane == 0) out[row] = s;
}

// ---------------------------------------------------------------------------
// Stage 1 of Ksum/Vsum, with Tsum fused in.
// Block = (c-chunk cs of 64, b). Phase 1: 64 row-sums of T[b, c0+r, :]
// (reads T once across the grid, coalesced float4). Phase 2: partial
// pK[b,cs,d] = sum_{c in chunk} Tsum[c] * Wk[c,d] (and pV with Wv).
// Grid (16, 32) = 512 blocks.
// ---------------------------------------------------------------------------
__global__ __launch_bounds__(256) void k_kv1(const float* __restrict__ T,
                                             const float* __restrict__ Wk,
                                             const float* __restrict__ Wv,
                                             float* __restrict__ pK,
                                             float* __restrict__ pV) {
    __shared__ float ts[64];
    const int cs  = blockIdx.x;
    const int b   = blockIdx.y;
    const int c0  = cs * 64;
    const int tid = threadIdx.x;
    const int w   = tid >> 6, lane = tid & 63;

    const float* Tb = T + ((long)b * Cc + c0) * Mc;
#pragma unroll 4
    for (int r = w * 16; r < w * 16 + 16; ++r) {
        const float* row = Tb + (long)r * Mc;
        float s = 0.f;
#pragma unroll
        for (int k = 0; k < 4; ++k) {
            float4 t = *(const float4*)&row[k * 256 + lane * 4];
            s += (t.x + t.y) + (t.z + t.w);
        }
#pragma unroll
        for (int off = 32; off; off >>= 1) s += __shfl_down(s, off, 64);
        if (lane == 0) ts[r] = s;
    }
    __syncthreads();

    const int d = tid;  // covers d and d+256
    float k1 = 0.f, k2 = 0.f, v1 = 0.f, v2 = 0.f;
#pragma unroll 4
    for (int c = 0; c < 64; ++c) {
        float t = ts[c];  // LDS broadcast
        const float* wkr = Wk + (long)(c0 + c) * Dc;
        const float* wvr = Wv + (long)(c0 + c) * DVc;
        k1 = fmaf(t, wkr[d],       k1);
        k2 = fmaf(t, wkr[d + 256], k2);
        v1 = fmaf(t, wvr[d],       v1);
        v2 = fmaf(t, wvr[d + 256], v2);
    }
    const long base = ((long)b * 16 + cs) * 512;
    pK[base + d] = k1;  pK[base + d + 256] = k2;
    pV[base + d] = v1;  pV[base + d + 256] = v2;
}

// Stage 2: Ksum/Vsum[b,d] = sum over 16 c-chunks. Grid 128 blocks.
__global__ __launch_bounds__(256) void k_kv2(const float* __restrict__ pK,
                                             const float* __restrict__ pV,
                                             float* __restrict__ Ksum,
                                             float* __restrict__ Vsum) {
    const int gid = blockIdx.x * 256 + threadIdx.x;  // 0..32767
    const int sel = gid >> 14;
    const int rem = gid & 16383;  // b*512 + d
    const float* p = (sel ? pV : pK) + (long)(rem >> 9) * 16 * 512 + (rem & 511);
    float s = 0.f;
#pragma unroll
    for (int i = 0; i < 16; ++i) s += p[i * 512];
    (sel ? Vsum : Ksum)[rem] = s;
}

// ---------------------------------------------------------------------------
// wqk[b,c] = sum_d Wq[c,d]*Ksum[b,d]. One wave per (b,c): lanes span d,
// coalesced Wq row reads, shuffle reduce. Grid 8192 blocks (32768 waves).
// ---------------------------------------------------------------------------
__global__ __launch_bounds__(256) void k_wqk(const float* __restrict__ Wq,
                                             const float* __restrict__ Ksum,
                                             float* __restrict__ wqk) {
    const int wid  = blockIdx.x * 4 + (threadIdx.x >> 6);  // b*1024 + c
    const int lane = threadIdx.x & 63;
    const float* wq = Wq + (long)(wid & 1023) * Dc;
    const float* ks = Ksum + (wid >> 10) * Dc;
    float s = 0.f;
#pragma unroll
    for (int k = 0; k < 4; ++k) {
        int d = k * 128 + lane * 2;
        float2 a = *(const float2*)&wq[d];
        float2 x = *(const float2*)&ks[d];
        s = fmaf(a.x, x.x, s);
        s = fmaf(a.y, x.y, s);
    }
#pragma unroll
    for (int off = 32; off; off >>= 1) s += __shfl_down(s, off, 64);
    if (lane == 0) wqk[wid] = s;
}

// ---------------------------------------------------------------------------
// vw[b,c] = sum_d Vsum[b,d]*Wout[d,c]. Stage 1: d split 8 ways (64 d each);
// threads span c (coalesced Wout rows), Vsum broadcast from LDS.
// Grid (8, 32) = 256 blocks. Stage 2 reduces the 8 partials.
// ---------------------------------------------------------------------------
__global__ __launch_bounds__(256) void k_vw1(const float* __restrict__ Wout,
                                             const float* __restrict__ Vsum,
                                             float* __restrict__ pVW) {
    __shared__ float vs[64];
    const int ds  = blockIdx.x;
    const int b   = blockIdx.y;
    const int d0  = ds * 64;
    const int tid = threadIdx.x;
    if (tid < 64) vs[tid] = Vsum[b * Dc + d0 + tid];
    __syncthreads();
    float a0 = 0.f, a1 = 0.f, a2 = 0.f, a3 = 0.f;
    const float* W0 = Wout + (long)d0 * Cc + tid;
#pragma unroll 4
    for (int d = 0; d < 64; ++d) {
        float v = vs[d];
        const float* wr = W0 + (long)d * Cc;
        a0 = fmaf(v, wr[0],   a0);
        a1 = fmaf(v, wr[256], a1);
        a2 = fmaf(v, wr[512], a2);
        a3 = fmaf(v, wr[768], a3);
    }
    const long base = ((long)b * 8 + ds) * 1024 + tid;
    pVW[base] = a0;  pVW[base + 256] = a1;
    pVW[base + 512] = a2;  pVW[base + 768] = a3;
}

__global__ __launch_bounds__(256) void k_vw2(const float* __restrict__ pVW,
                                             float* __restrict__ vw) {
    const int gid = blockIdx.x * 256 + threadIdx.x;  // b*1024 + c
    const float* p = pVW + (long)(gid >> 10) * 8 * 1024 + (gid & 1023);
    float s = 0.f;
#pragma unroll
    for (int i = 0; i < 8; ++i) s += p[i * 1024];
    vw[gid] = s;
}

// ---------------------------------------------------------------------------
// Fused final: per (b, 64-m tile):
//   qk[i]  = sum_c T[b,c,i] * wqk[b,c]
//   w[i]   = sum_r softmax_r(scale*qk[i]*rsum[r]) * rsum[r]
//   Out[b,c,i] = w[i] * vw[b,c]   (nontemporal store: keep T in L3)
// ---------------------------------------------------------------------------
__global__ __launch_bounds__(256) void k_final(const float* __restrict__ T,
                                               const float* __restrict__ wqk,
                                               const float* __restrict__ vw,
                                               const float* __restrict__ rsum,
                                               float* __restrict__ Out,
                                               float scale) {
    __shared__ float rs[64];
    __shared__ float part[16][72];
    __shared__ float wsh[64];

    const int b  = blockIdx.y;
    const int m0 = blockIdx.x * 64;
    const int il = threadIdx.x & 15;
    const int cs = threadIdx.x >> 4;

    if (threadIdx.x < 64) rs[threadIdx.x] = rsum[threadIdx.x];

    const float* wq  = wqk + b * Cc;
    const float* Tbm = T + (long)b * Cc * Mc + m0 + il * 4;

    float4 acc = make_float4(0.f, 0.f, 0.f, 0.f);
#pragma unroll 4
    for (int c = cs; c < Cc; c += 16) {
        float4 t = *(const float4*)&Tbm[(long)c * Mc];
        float wc = wq[c];
        acc.x = fmaf(t.x, wc, acc.x);
        acc.y = fmaf(t.y, wc, acc.y);
        acc.z = fmaf(t.z, wc, acc.z);
        acc.w = fmaf(t.w, wc, acc.w);
    }
    *(float4*)&part[cs][il * 4] = acc;
    __syncthreads();

    if (threadIdx.x < 64) {
        const int i = threadIdx.x;
        float q = 0.f;
#pragma unroll
        for (int k = 0; k < 16; ++k) q += part[k][i];
        q *= scale;
        float mx = -1e30f;
#pragma unroll
        for (int r = 0; r < 64; ++r) mx = fmaxf(mx, q * rs[r]);
        float se = 0.f, sw = 0.f;
#pragma unroll
        for (int r = 0; r < 64; ++r) {
            float e = __expf(q * rs[r] - mx);
            se += e;
            sw = fmaf(e, rs[r], sw);
        }
        wsh[i] = sw / se;
    }
    __syncthreads();

    const float* vwb = vw + b * Cc;
    float* Ob = Out + (long)b * Cc * Mc + m0 + il * 4;
    float4 w4 = *(const float4*)&wsh[il * 4];
#pragma unroll 4
    for (int c = cs; c < Cc; c += 16) {
        float v = vwb[c];
        f4 o = {w4.x * v, w4.y * v, w4.z * v, w4.w * v};
        __builtin_nontemporal_store(o, (f4*)&Ob[(long)c * Mc]);
    }
}

extern "C" void kernel_launch(void* const* d_in, const int* in_sizes, int n_in,
                              void* d_out, int out_size, void* d_ws, size_t ws_size,
                              hipStream_t stream) {
    const float* T     = (const float*)d_in[0];  // (B,C,M)
    const float* Wq    = (const float*)d_in[1];  // (C,D)
    const float* Wk    = (const float*)d_in[2];  // (C,D)
    const float* Wv    = (const float*)d_in[3];  // (C,DV)
    const float* Wout  = (const float*)d_in[4];  // (DV,C)
    const float* Rfull = (const float*)d_in[5];  // (R,M)
    float* Out = (float*)d_out;

    float* ws   = (float*)d_ws;
    float* rsum = ws;                  // 64
    float* Ksum = rsum + Rc;           // 16384
    float* Vsum = Ksum + Bc * Dc;      // 16384
    float* wqk  = Vsum + Bc * DVc;     // 32768
    float* vw   = wqk + Bc * Cc;       // 32768
    float* pK   = vw + Bc * Cc;        // 32*16*512 = 262144
    float* pV   = pK + 262144;         // 262144
    float* pVW  = pV + 262144;         // 32*8*1024 = 262144

    // 1) kv stage 1 (fused Tsum): reads all of T once
    k_kv1<<<dim3(16, Bc), 256, 0, stream>>>(T, Wk, Wv, pK, pV);
    // 2) rsum[r] = sum_m R_full[r,m]
    k_rowsum<<<Rc / 4, 256, 0, stream>>>(Rfull, rsum, Rc);
    // 3) kv stage 2
    k_kv2<<<128, 256, 0, stream>>>(pK, pV, Ksum, Vsum);
    // 4) wqk
    k_wqk<<<(Bc * Cc) / 4, 256, 0, stream>>>(Wq, Ksum, wqk);
    // 5) vw stages
    k_vw1<<<dim3(8, Bc), 256, 0, stream>>>(Wout, Vsum, pVW);
    k_vw2<<<128, 256, 0, stream>>>(pVW, vw);
    // 6) fused scores/softmax/output
    const float scale = 1.0f / sqrtf((float)Dc);
    k_final<<<dim3(Mc / 64, Bc), 256, 0, stream>>>(T, wqk, vw, rsum, Out, scale);
}